// Round 1
// baseline (122.458 us; speedup 1.0000x reference)
//
#include <hip/hip_runtime.h>

// Problem: B=16, C=3, H=512, W=512 fp32. Output [B,C,4] = {tp,tn,fp,fn}.
// tp=sum(p*t); fp=sum(p)-tp; fn=sum(t)-tp; tn=N-sum(p)-sum(t)+tp.
// Single pass accumulating (sum_p, sum_t, sum_pt) per (b,c) slice.

constexpr int N_PER_SLICE = 512 * 512;        // 262144 elements per slice
constexpr int SLICES      = 16 * 3;           // 48
constexpr int BPS         = 32;               // blocks per slice
constexpr int CHUNK       = N_PER_SLICE / BPS;// 8192 floats per block
constexpr int THREADS     = 256;

__global__ __launch_bounds__(THREADS) void cm_partial(
    const float* __restrict__ p, const float* __restrict__ t,
    float* __restrict__ ws) {
    const int s = blockIdx.x / BPS;           // slice index (uniform per block)
    const int c = blockIdx.x % BPS;           // chunk within slice
    const size_t base = (size_t)s * N_PER_SLICE + (size_t)c * CHUNK;
    const float4* __restrict__ p4 = reinterpret_cast<const float4*>(p + base);
    const float4* __restrict__ t4 = reinterpret_cast<const float4*>(t + base);

    float sp = 0.f, st = 0.f, spt = 0.f;
    // CHUNK/4 = 2048 float4 per block -> 8 per thread
    #pragma unroll 8
    for (int i = threadIdx.x; i < CHUNK / 4; i += THREADS) {
        float4 a = p4[i];
        float4 b = t4[i];
        sp  += (a.x + a.y) + (a.z + a.w);
        st  += (b.x + b.y) + (b.z + b.w);
        spt += a.x * b.x + a.y * b.y + a.z * b.z + a.w * b.w;
    }

    // 64-lane wave reduce
    #pragma unroll
    for (int off = 32; off > 0; off >>= 1) {
        sp  += __shfl_down(sp,  off);
        st  += __shfl_down(st,  off);
        spt += __shfl_down(spt, off);
    }

    __shared__ float red[3][THREADS / 64];
    const int wave = threadIdx.x >> 6;
    const int lane = threadIdx.x & 63;
    if (lane == 0) {
        red[0][wave] = sp;
        red[1][wave] = st;
        red[2][wave] = spt;
    }
    __syncthreads();
    if (threadIdx.x == 0) {
        float tsp  = (red[0][0] + red[0][1]) + (red[0][2] + red[0][3]);
        float tst  = (red[1][0] + red[1][1]) + (red[1][2] + red[1][3]);
        float tspt = (red[2][0] + red[2][1]) + (red[2][2] + red[2][3]);
        atomicAdd(&ws[s * 3 + 0], tsp);
        atomicAdd(&ws[s * 3 + 1], tst);
        atomicAdd(&ws[s * 3 + 2], tspt);
    }
}

__global__ void cm_final(const float* __restrict__ ws, float* __restrict__ out) {
    int s = threadIdx.x;
    if (s < SLICES) {
        float sp  = ws[s * 3 + 0];
        float st  = ws[s * 3 + 1];
        float spt = ws[s * 3 + 2];
        float tp = spt;
        float fp = sp - spt;
        float fn = st - spt;
        float tn = (float)N_PER_SLICE - sp - st + spt;
        out[s * 4 + 0] = tp;
        out[s * 4 + 1] = tn;
        out[s * 4 + 2] = fp;
        out[s * 4 + 3] = fn;
    }
}

extern "C" void kernel_launch(void* const* d_in, const int* in_sizes, int n_in,
                              void* d_out, int out_size, void* d_ws, size_t ws_size,
                              hipStream_t stream) {
    const float* y_pred = (const float*)d_in[0];
    const float* y_true = (const float*)d_in[1];
    float* out = (float*)d_out;
    float* ws  = (float*)d_ws;

    // ws is poisoned 0xAA before every launch -> zero the accumulators.
    hipMemsetAsync(ws, 0, SLICES * 3 * sizeof(float), stream);

    cm_partial<<<SLICES * BPS, THREADS, 0, stream>>>(y_pred, y_true, ws);
    cm_final<<<1, 64, 0, stream>>>(ws, out);
}

// Round 2
// 113.563 us; speedup vs baseline: 1.0783x; 1.0783x over previous
//
#include <hip/hip_runtime.h>

// Problem: B=16, C=3, H=512, W=512 fp32. Output [B,C,4] = {tp,tn,fp,fn}.
// tp=sum(p*t); fp=sum(p)-tp; fn=sum(t)-tp; tn=N-sum(p)-sum(t)+tp.
// Pass 1: per-block (Sp, St, Spt) partials -> unique d_ws slots (no atomics,
//         no pre-zero). Pass 2: 48 tiny blocks fold 32 partials each.

constexpr int N_PER_SLICE = 512 * 512;         // 262144 elements per slice
constexpr int SLICES      = 16 * 3;            // 48
constexpr int BPS         = 32;                // blocks per slice
constexpr int CHUNK       = N_PER_SLICE / BPS; // 8192 floats per block
constexpr int THREADS     = 256;

__global__ __launch_bounds__(THREADS) void cm_partial(
    const float* __restrict__ p, const float* __restrict__ t,
    float4* __restrict__ ws) {
    const int s = blockIdx.x / BPS;            // slice index
    const int c = blockIdx.x % BPS;            // chunk within slice
    const size_t base = (size_t)s * N_PER_SLICE + (size_t)c * CHUNK;
    const float4* __restrict__ p4 = reinterpret_cast<const float4*>(p + base);
    const float4* __restrict__ t4 = reinterpret_cast<const float4*>(t + base);

    float sp = 0.f, st = 0.f, spt = 0.f;
    // CHUNK/4 = 2048 float4 per block -> 8 per thread, fully coalesced
    #pragma unroll 8
    for (int i = threadIdx.x; i < CHUNK / 4; i += THREADS) {
        float4 a = p4[i];
        float4 b = t4[i];
        sp  += (a.x + a.y) + (a.z + a.w);
        st  += (b.x + b.y) + (b.z + b.w);
        spt += a.x * b.x + a.y * b.y + a.z * b.z + a.w * b.w;
    }

    // 64-lane wave reduce
    #pragma unroll
    for (int off = 32; off > 0; off >>= 1) {
        sp  += __shfl_down(sp,  off);
        st  += __shfl_down(st,  off);
        spt += __shfl_down(spt, off);
    }

    __shared__ float red[3][THREADS / 64];
    const int wave = threadIdx.x >> 6;
    const int lane = threadIdx.x & 63;
    if (lane == 0) {
        red[0][wave] = sp;
        red[1][wave] = st;
        red[2][wave] = spt;
    }
    __syncthreads();
    if (threadIdx.x == 0) {
        float tsp  = (red[0][0] + red[0][1]) + (red[0][2] + red[0][3]);
        float tst  = (red[1][0] + red[1][1]) + (red[1][2] + red[1][3]);
        float tspt = (red[2][0] + red[2][1]) + (red[2][2] + red[2][3]);
        ws[blockIdx.x] = make_float4(tsp, tst, tspt, 0.f);  // unique slot
    }
}

__global__ __launch_bounds__(64) void cm_final(
    const float4* __restrict__ ws, float4* __restrict__ out) {
    const int s = blockIdx.x;       // slice
    const int l = threadIdx.x;      // lane 0..63
    float4 v = (l < BPS) ? ws[s * BPS + l] : make_float4(0.f, 0.f, 0.f, 0.f);
    float sp = v.x, st = v.y, spt = v.z;
    #pragma unroll
    for (int off = 32; off > 0; off >>= 1) {
        sp  += __shfl_down(sp,  off);
        st  += __shfl_down(st,  off);
        spt += __shfl_down(spt, off);
    }
    if (l == 0) {
        float tp = spt;
        float fp = sp - spt;
        float fn = st - spt;
        float tn = (float)N_PER_SLICE - sp - st + spt;
        out[s] = make_float4(tp, tn, fp, fn);   // [tp, tn, fp, fn]
    }
}

extern "C" void kernel_launch(void* const* d_in, const int* in_sizes, int n_in,
                              void* d_out, int out_size, void* d_ws, size_t ws_size,
                              hipStream_t stream) {
    const float* y_pred = (const float*)d_in[0];
    const float* y_true = (const float*)d_in[1];
    float4* ws  = (float4*)d_ws;
    float4* out = (float4*)d_out;

    cm_partial<<<SLICES * BPS, THREADS, 0, stream>>>(y_pred, y_true, ws);
    cm_final<<<SLICES, 64, 0, stream>>>(ws, out);
}